// Round 16
// baseline (93.067 us; speedup 1.0000x reference)
//
#include <hip/hip_runtime.h>

typedef __bf16 bf16x8 __attribute__((ext_vector_type(8)));
typedef float  f32x16 __attribute__((ext_vector_type(16)));
typedef unsigned short u16;

#define NB    512
#define SEQ   128
#define EMB   300

// ws layout: feats (512*300 f32 = 614400 B) at 0; weight streams after.
#define OFF_WU 614400

// A tile: 68 staged rows + 1 guard, 320 bf16/row, stride 656 B linear (r10/r14 best).
#define AROW 656
#define A_BYTES (69 * AROW)     // 45264

// 32x32x16 MFMA. Exact-K per-(wave,pass) contiguous streams; 1KB per (kt16, tile):
//   byte = chunkbase + (kt*NTW + tloc)*1024 + lane*16
//   -> W[f = FL0 + tloc*32 + (lane&31)][kk = kt*16 + (lane>>5)*8 + j], kk over KH*320
// passes: P0 w3 t0-3 (NTW4,KH3) @0 ; P1 w4 t0-2 (NTW3,KH4) @245760 ;
//         P2 w4 t3 (NTW1,KH4) @491520 ; P3 w5 t0-1 (NTW2,KH5) @573440 ;
//         P4 w5 t2-3 (NTW2,KH5) @778240 ; total 983040 B (= r1-proven ws budget)
#define PREP_TOT 491520

__device__ __forceinline__ u16 f2bf(float f) {
  unsigned u = __builtin_bit_cast(unsigned, f);
  return (u16)((u + 0x7fffu + ((u >> 16) & 1u)) >> 16);   // RNE
}

__global__ void prep_weights(const float* __restrict__ w3, const float* __restrict__ w4,
                             const float* __restrict__ w5, u16* __restrict__ wu) {
  int idx = blockIdx.x * blockDim.x + threadIdx.x;
  if (idx >= PREP_TOT) return;
  const int cum[6]  = {0, 122880, 245760, 286720, 389120, 491520};
  const int ntwA[5] = {4, 3, 1, 2, 2};
  const int khA[5]  = {3, 4, 4, 5, 5};
  const int fl0A[5] = {0, 0, 96, 0, 64};
  int p = 0;
  #pragma unroll
  for (int q = 0; q < 4; ++q) if (idx >= cum[q + 1]) p = q + 1;
  int rem = idx - cum[p];
  int ntw = ntwA[p], kh = khA[p];
  int j = rem & 7, l = (rem >> 3) & 63, c = rem >> 9;
  int tloc = c % ntw, kt = c / ntw;
  int f  = fl0A[p] + tloc * 32 + (l & 31);
  int kk = kt * 16 + ((l >> 5) << 3) + j;
  int dk = kk / 320, e = kk - dk * 320;        // branch-LOCAL kernel row (exact K)
  float v = 0.f;
  if (f < 100 && e < 300) {
    if (kh == 3)      v = w3[(f * 3 + dk) * 300 + e];
    else if (kh == 4) v = w4[(f * 4 + dk) * 300 + e];
    else              v = w5[(f * 5 + dk) * 300 + e];
  }
  wu[idx] = f2bf(v);
}

// One pass: wave = 2 M-tiles(32) x NTW N-tiles(32), exactly KH*20 K16-steps.
// A double-set reg prefetch (aC/aN); B 2-deep rolling (bC/bN, refill consumed set
// with chunk t+2; STEPN = no refill on last 2 steps, keeps reads in-stream);
// setprio around burst; barrier-free; all waits compiler-counted.
template<int NTW, int KH>
__device__ __forceinline__ void kloop_epi(const char* xs, const char* gstream,
                                          int l, int s0, int fl0,
                                          const float* __restrict__ bias, int sval,
                                          int foff, int b, float* __restrict__ feats) {
  const int lo32 = l & 31, hi2 = l >> 5;
  constexpr int DK0 = 5 - KH;                  // k5-aligned window start row

  f32x16 acc[2][NTW];
  #pragma unroll
  for (int mt = 0; mt < 2; ++mt)
    #pragma unroll
    for (int j = 0; j < NTW; ++j)
      #pragma unroll
      for (int r = 0; r < 16; ++r) acc[mt][j][r] = 0.f;

  bf16x8 aC[2], aN[2], bC[NTW], bN[NTW];

  // B prologue: step 0 -> bC, step 1 -> bN; gB left at step 2
  const char* gB = gstream + l * 16;
  #pragma unroll
  for (int j = 0; j < NTW; ++j) bC[j] = *reinterpret_cast<const bf16x8*>(gB + j * 1024);
  gB += NTW * 1024;
  #pragma unroll
  for (int j = 0; j < NTW; ++j) bN[j] = *reinterpret_cast<const bf16x8*>(gB + j * 1024);
  gB += NTW * 1024;

  // A base: row r = mt*32 + lo32 + DK0 (+dk), byte = r*656 + hi2*16 (+ eg*32 imm)
  int abase[2];
  #pragma unroll
  for (int mt = 0; mt < 2; ++mt) abase[mt] = (mt * 32 + lo32 + DK0) * AROW + hi2 * 16;

  // A prologue: (dk0, eg0) -> aC
  #pragma unroll
  for (int mt = 0; mt < 2; ++mt)
    aC[mt] = *reinterpret_cast<const bf16x8*>(xs + abase[mt]);

#define MFMAS(ACON, BSET) {                                                    \
    __builtin_amdgcn_s_setprio(1);                                             \
    _Pragma("unroll") for (int mt = 0; mt < 2; ++mt)                           \
    _Pragma("unroll") for (int j = 0; j < NTW; ++j)                            \
      acc[mt][j] = __builtin_amdgcn_mfma_f32_32x32x16_bf16(ACON[mt], BSET[j],  \
                                                           acc[mt][j], 0, 0, 0); \
    __builtin_amdgcn_s_setprio(0); }

#define STEP(AOFF, ACON, ANEX, BSET) {                                         \
    _Pragma("unroll") for (int mt = 0; mt < 2; ++mt)                           \
      ANEX[mt] = *reinterpret_cast<const bf16x8*>(xs + abase[mt] + (AOFF));    \
    MFMAS(ACON, BSET)                                                          \
    _Pragma("unroll") for (int j = 0; j < NTW; ++j)                            \
      BSET[j] = *reinterpret_cast<const bf16x8*>(gB + j * 1024);               \
    gB += NTW * 1024; }

#define STEPN(AOFF, ACON, ANEX, BSET) {                                        \
    _Pragma("unroll") for (int mt = 0; mt < 2; ++mt)                           \
      ANEX[mt] = *reinterpret_cast<const bf16x8*>(xs + abase[mt] + (AOFF));    \
    MFMAS(ACON, BSET) }

  // 20 steps per dk row: eg prefetch offsets 32..608, then 656 (next row, eg0)
#define BODY() {                                                               \
    STEP( 32, aC, aN, bC) STEP( 64, aN, aC, bN) STEP( 96, aC, aN, bC)          \
    STEP(128, aN, aC, bN) STEP(160, aC, aN, bC) STEP(192, aN, aC, bN)          \
    STEP(224, aC, aN, bC) STEP(256, aN, aC, bN) STEP(288, aC, aN, bC)          \
    STEP(320, aN, aC, bN) STEP(352, aC, aN, bC) STEP(384, aN, aC, bN)          \
    STEP(416, aC, aN, bC) STEP(448, aN, aC, bN) STEP(480, aC, aN, bC)          \
    STEP(512, aN, aC, bN) STEP(544, aC, aN, bC) STEP(576, aN, aC, bN)          \
    STEP(608, aC, aN, bC) STEP(656, aN, aC, bN)                                \
    _Pragma("unroll") for (int mt = 0; mt < 2; ++mt) abase[mt] += AROW; }

#define BODY_LAST() {                                                          \
    STEP( 32, aC, aN, bC) STEP( 64, aN, aC, bN) STEP( 96, aC, aN, bC)          \
    STEP(128, aN, aC, bN) STEP(160, aC, aN, bC) STEP(192, aN, aC, bN)          \
    STEP(224, aC, aN, bC) STEP(256, aN, aC, bN) STEP(288, aC, aN, bC)          \
    STEP(320, aN, aC, bN) STEP(352, aC, aN, bC) STEP(384, aN, aC, bN)          \
    STEP(416, aC, aN, bC) STEP(448, aN, aC, bN) STEP(480, aC, aN, bC)          \
    STEP(512, aN, aC, bN) STEP(544, aC, aN, bC) STEP(576, aN, aC, bN)          \
    STEPN(608, aC, aN, bC) STEPN(656, aN, aC, bN) }

  if constexpr (KH == 3) { BODY() BODY() BODY_LAST() }
  if constexpr (KH == 4) { BODY() BODY() BODY() BODY_LAST() }
  if constexpr (KH == 5) { BODY() BODY() BODY() BODY() BODY_LAST() }
#undef BODY
#undef BODY_LAST
#undef STEP
#undef STEPN
#undef MFMAS

  // epilogue: bias + relu + masked max over this block's 64 s-positions.
  // C/D 32x32: col = lane&31 (filter), row = (r&3) + 8*(r>>2) + 4*(lane>>5)
  #pragma unroll
  for (int j = 0; j < NTW; ++j) {
    int f = fl0 + j * 32 + lo32;
    if (f < 100) {
      float bia  = bias[f];
      float cmax = 0.f;                        // relu floor
      #pragma unroll
      for (int mt = 0; mt < 2; ++mt)
        #pragma unroll
        for (int r = 0; r < 16; ++r) {
          int s = s0 + mt * 32 + (r & 3) + 8 * (r >> 2) + 4 * hi2;
          float v = acc[mt][j][r] + bia;
          if (s < sval) cmax = fmaxf(cmax, v);
        }
      cmax = fmaxf(cmax, __shfl_xor(cmax, 32));
      if (hi2 == 0)
        atomicMax((int*)&feats[b * 300 + foff + f], __float_as_int(fmaxf(cmax, 0.f)));
    }
  }
}

// Block = (sample, s-half): M=64 = 2 M-tiles of 32, exact-K per branch, 4 waves
// balanced 240/240/280/200 kt16-units. 32x32x16 MFMA: 2x FLOP per issue slot,
// half the A-reads and B-refills per FLOP vs 16x16x32. Barrier-free K-loop.
__global__ __launch_bounds__(256, 2)
void conv_max_kernel(const float* __restrict__ x, const u16* __restrict__ wu,
                     const float* __restrict__ b3, const float* __restrict__ b4,
                     const float* __restrict__ b5, float* __restrict__ feats) {
  __shared__ __align__(16) char xs[A_BYTES];
  const int bid = blockIdx.x;
  const int b = bid >> 1, s0 = (bid & 1) * 64;
  const int tid = threadIdx.x;
  const int l = tid & 63, w = tid >> 6;
  const float* xb = x + (size_t)b * (SEQ * EMB);
  const char*  wB = (const char*)wu;

  // stage A: rows s0-2 .. s0+65 (68), 656 B stride, linear
  for (int t = tid; t < 68 * 80; t += 256) {
    int r = t / 80, cg = t - r * 80;
    int xr = s0 - 2 + r;
    float4 v = make_float4(0.f, 0.f, 0.f, 0.f);
    if (xr >= 0 && xr < SEQ && cg < 75)
      v = *reinterpret_cast<const float4*>(xb + xr * EMB + cg * 4);
    ushort4 h;
    h.x = f2bf(v.x); h.y = f2bf(v.y); h.z = f2bf(v.z); h.w = f2bf(v.w);
    *reinterpret_cast<ushort4*>(xs + r * AROW + cg * 8) = h;
  }
  __syncthreads();   // the only barrier: A visible to all 4 waves

  if (w == 0) {
    kloop_epi<4, 3>(xs, wB + 0,      l, s0,  0, b3, 126,   0, b, feats);
  } else if (w == 1) {
    kloop_epi<3, 4>(xs, wB + 245760, l, s0,  0, b4, 127, 100, b, feats);
  } else if (w == 2) {
    kloop_epi<1, 4>(xs, wB + 491520, l, s0, 96, b4, 127, 100, b, feats);
    kloop_epi<2, 5>(xs, wB + 573440, l, s0,  0, b5, 128, 200, b, feats);
  } else {
    kloop_epi<2, 5>(xs, wB + 778240, l, s0, 64, b5, 128, 200, b, feats);
  }
}

// feats[512,300] @ Wfc[5,300]^T + bfc -> log_softmax. One wave per row.
__global__ void fc_kernel(const float* __restrict__ feats, const float* __restrict__ Wfc,
                          const float* __restrict__ bfc, float* __restrict__ out) {
  const int b = blockIdx.x, l = threadIdx.x;
  float acc[5] = {0.f, 0.f, 0.f, 0.f, 0.f};
  for (int e = l; e < 300; e += 64) {
    float fv = feats[b * 300 + e];
    #pragma unroll
    for (int c = 0; c < 5; ++c) acc[c] += fv * Wfc[c * 300 + e];
  }
  #pragma unroll
  for (int off = 32; off; off >>= 1) {
    #pragma unroll
    for (int c = 0; c < 5; ++c) acc[c] += __shfl_down(acc[c], off);
  }
  if (l == 0) {
    float lg[5], m = -1e30f;
    #pragma unroll
    for (int c = 0; c < 5; ++c) { lg[c] = acc[c] + bfc[c]; m = fmaxf(m, lg[c]); }
    float se = 0.f;
    #pragma unroll
    for (int c = 0; c < 5; ++c) se += expf(lg[c] - m);
    float ls = logf(se);
    #pragma unroll
    for (int c = 0; c < 5; ++c) out[b * 5 + c] = lg[c] - m - ls;
  }
}

extern "C" void kernel_launch(void* const* d_in, const int* in_sizes, int n_in,
                              void* d_out, int out_size, void* d_ws, size_t ws_size,
                              hipStream_t stream) {
  const float* x   = (const float*)d_in[0];
  const float* w3  = (const float*)d_in[1];
  const float* b3  = (const float*)d_in[2];
  const float* w4  = (const float*)d_in[3];
  const float* b4  = (const float*)d_in[4];
  const float* w5  = (const float*)d_in[5];
  const float* b5  = (const float*)d_in[6];
  const float* Wfc = (const float*)d_in[7];
  const float* bfc = (const float*)d_in[8];
  float* out = (float*)d_out;

  float* feats = (float*)d_ws;                         // 614400 B at offset 0
  u16*   wu    = (u16*)((char*)d_ws + OFF_WU);         // 983040 B streams

  hipMemsetAsync(feats, 0, NB * 300 * sizeof(float), stream);  // atomicMax target

  prep_weights<<<(PREP_TOT + 255) / 256, 256, 0, stream>>>(w3, w4, w5, wu);
  conv_max_kernel<<<NB * 2, 256, 0, stream>>>(x, wu, b3, b4, b5, feats);
  fc_kernel<<<NB, 64, 0, stream>>>(feats, Wfc, bfc, out);
}

// Round 17
// 70.389 us; speedup vs baseline: 1.3222x; 1.3222x over previous
//
#include <hip/hip_runtime.h>

typedef __bf16 bf16x8 __attribute__((ext_vector_type(8)));
typedef float  f32x4  __attribute__((ext_vector_type(4)));
typedef unsigned short u16;

#define NB    512
#define SEQ   128
#define EMB   300

// A tile: 68 staged rows + 1 guard, 320 bf16/row, stride 656 B (r10/r14-verified:
// linear addressing beats XOR swizzle despite ~2-way residual conflicts).
#define AROW 656
#define A_BYTES (69 * AROW)     // 45264

// Per-(wave,pass) contiguous exact-K weight streams (r14-verified):
//   stream elem = (kt*NTW + tloc)*512 + lane*8 + j
//   -> W[f = FL0 + tloc*16 + (lane&15)][kk = kt*32 + (lane>>4)*8 + j], kk over KH*320
// wave 0: P0 = w3 tiles 0-3 (NTW4,KH3) ; P1 = w3 tiles 4-6 (NTW3,KH3)
// wave 1: P2 = w4 tiles 0-3 (NTW4,KH4) ; P3 = w5 tile  0   (NTW1,KH5)
// wave 2: P4 = w4 tiles 4-6 (NTW3,KH4) ; P5 = w5 tiles 1-2 (NTW2,KH5)
// wave 3: P6 = w5 tiles 3-6 (NTW4,KH5)
#define PREP_TOT 430080
#define OFF_FEATS 876544                   // 860160 stream bytes + 16KB tail guard
#define FEATS_N (NB * 300)                 // 153600 f32

__device__ __forceinline__ u16 f2bf(float f) {
  unsigned u = __builtin_bit_cast(unsigned, f);
  return (u16)((u + 0x7fffu + ((u >> 16) & 1u)) >> 16);   // RNE
}

// Also zeroes feats (atomicMax target) -- replaces the separate memset dispatch.
__global__ void prep_weights(const float* __restrict__ w3, const float* __restrict__ w4,
                             const float* __restrict__ w5, u16* __restrict__ wu,
                             float* __restrict__ feats) {
  int idx = blockIdx.x * blockDim.x + threadIdx.x;
  if (idx < FEATS_N) feats[idx] = 0.f;
  if (idx >= PREP_TOT) return;
  const int cum[8]  = {0, 61440, 107520, 189440, 215040, 276480, 327680, 430080};
  const int ntwA[7] = {4, 3, 4, 1, 3, 2, 4};
  const int khA[7]  = {3, 3, 4, 5, 4, 5, 5};
  const int fl0A[7] = {0, 64, 0, 0, 64, 16, 48};
  int p = 0;
  #pragma unroll
  for (int q = 0; q < 6; ++q) if (idx >= cum[q + 1]) p = q + 1;
  int rem = idx - cum[p];
  int ntw = ntwA[p], kh = khA[p];
  int j = rem & 7, l = (rem >> 3) & 63, t = rem >> 9;
  int tloc = t % ntw, kt = t / ntw;
  int fl = fl0A[p] + tloc * 16 + (l & 15);
  int kk = kt * 32 + ((l >> 4) << 3) + j;
  int dk = kk / 320, e = kk - dk * 320;        // branch-LOCAL kernel row (exact K)
  float v = 0.f;
  if (fl < 100 && e < 300) {
    if (kh == 3)      v = w3[(fl * 3 + dk) * 300 + e];
    else if (kh == 4) v = w4[(fl * 4 + dk) * 300 + e];
    else              v = w5[(fl * 5 + dk) * 300 + e];
  }
  wu[idx] = f2bf(v);
}

// One pass: wave = 4 M-tiles x NTW N-tiles over exactly KH*10 K-steps.
// r14 schedule frozen: A double-set reg prefetch (aC/aN), B 4-set rolling refill
// (1 chunk consumed + 1 refilled per step), setprio around the burst, no fences,
// no barriers; all waits compiler-counted. Acc freed per pass (epilogue inside).
template<int NTW, int KH>
__device__ __forceinline__ void kloop_epi(const char* xs, const char* gstream,
                                          int l, int s0, int fl0,
                                          const float* __restrict__ bias, int sval,
                                          int foff, int b, float* __restrict__ feats) {
  const int lo = l & 15, hi = l >> 4;
  constexpr int DK0 = 5 - KH;                  // k5-aligned window start row

  f32x4 acc[4][NTW];
  #pragma unroll
  for (int mt = 0; mt < 4; ++mt)
    #pragma unroll
    for (int j = 0; j < NTW; ++j) acc[mt][j] = (f32x4){0.f, 0.f, 0.f, 0.f};

  bf16x8 aC[4], aN[4], b0[NTW], b1[NTW], b2[NTW], b3s[NTW];

  // B prologue: chunks 0..3 -> sets; gB left at chunk 4
  const char* gB = gstream + l * 16;
  #pragma unroll
  for (int j = 0; j < NTW; ++j) b0[j]  = *reinterpret_cast<const bf16x8*>(gB + j * 1024);
  gB += NTW * 1024;
  #pragma unroll
  for (int j = 0; j < NTW; ++j) b1[j]  = *reinterpret_cast<const bf16x8*>(gB + j * 1024);
  gB += NTW * 1024;
  #pragma unroll
  for (int j = 0; j < NTW; ++j) b2[j]  = *reinterpret_cast<const bf16x8*>(gB + j * 1024);
  gB += NTW * 1024;
  #pragma unroll
  for (int j = 0; j < NTW; ++j) b3s[j] = *reinterpret_cast<const bf16x8*>(gB + j * 1024);
  gB += NTW * 1024;

  // A base: row r = mt*16 + lo + DK0 (+dk), byte = r*656 + hi*16 (+ eg*64 imm)
  int abase[4];
  #pragma unroll
  for (int mt = 0; mt < 4; ++mt) abase[mt] = (mt * 16 + lo + DK0) * AROW + hi * 16;

  // A prologue: (dk0, eg0) -> aC
  #pragma unroll
  for (int mt = 0; mt < 4; ++mt)
    aC[mt] = *reinterpret_cast<const bf16x8*>(xs + abase[mt]);

#define STEP(AOFF, ACON, ANEX, BSET) {                                         \
    _Pragma("unroll") for (int mt = 0; mt < 4; ++mt)                           \
      ANEX[mt] = *reinterpret_cast<const bf16x8*>(xs + abase[mt] + (AOFF));    \
    __builtin_amdgcn_s_setprio(1);                                             \
    _Pragma("unroll") for (int mt = 0; mt < 4; ++mt)                           \
    _Pragma("unroll") for (int j = 0; j < NTW; ++j)                            \
      acc[mt][j] = __builtin_amdgcn_mfma_f32_16x16x32_bf16(ACON[mt], BSET[j],  \
                                                           acc[mt][j], 0, 0, 0); \
    __builtin_amdgcn_s_setprio(0);                                             \
    _Pragma("unroll") for (int j = 0; j < NTW; ++j)                            \
      BSET[j] = *reinterpret_cast<const bf16x8*>(gB + j * 1024);               \
    gB += NTW * 1024; }

  // body d consumes 10 steps; B-set rotation start = (10d)%4 -> even d: 0, odd d: 2
#define BODY(SA, SB, SC, SD) {                                                 \
    STEP( 64, aC, aN, SA) STEP(128, aN, aC, SB) STEP(192, aC, aN, SC)          \
    STEP(256, aN, aC, SD) STEP(320, aC, aN, SA) STEP(384, aN, aC, SB)          \
    STEP(448, aC, aN, SC) STEP(512, aN, aC, SD) STEP(576, aC, aN, SA)          \
    STEP(656, aN, aC, SB)                                                      \
    _Pragma("unroll") for (int mt = 0; mt < 4; ++mt) abase[mt] += AROW; }

  BODY(b0, b1, b2, b3s)                        // dk 0
  BODY(b2, b3s, b0, b1)                        // dk 1
  BODY(b0, b1, b2, b3s)                        // dk 2
  if constexpr (KH >= 4) { BODY(b2, b3s, b0, b1) }   // dk 3
  if constexpr (KH == 5) { BODY(b0, b1, b2, b3s) }   // dk 4
  // tail: B refills over-read into the next stream / 16KB guard (never consumed);
  // final A prefetch reads guard row 68 (never consumed).
#undef BODY
#undef STEP

  // epilogue: bias + relu + masked max over this block's 64 s-positions
  #pragma unroll
  for (int j = 0; j < NTW; ++j) {
    int fl = fl0 + j * 16 + lo;
    if (fl < 100) {
      float bia  = bias[fl];
      float cmax = 0.f;                        // relu floor
      #pragma unroll
      for (int mt = 0; mt < 4; ++mt)
        #pragma unroll
        for (int ii = 0; ii < 4; ++ii) {
          int s = s0 + mt * 16 + hi * 4 + ii;  // C/D: row=(l>>4)*4+ii, col=l&15
          float v = acc[mt][j][ii] + bia;
          if (s < sval) cmax = fmaxf(cmax, v);
        }
      cmax = fmaxf(cmax, __shfl_xor(cmax, 16));
      cmax = fmaxf(cmax, __shfl_xor(cmax, 32));
      if (hi == 0)
        atomicMax((int*)&feats[b * 300 + foff + fl], __float_as_int(fmaxf(cmax, 0.f)));
    }
  }
}

// Block = (sample, s-half): M=64, exact-K per branch. 4 waves, 1-2 passes each
// (210/210/220/200 kt-tile units). Best measured structure (r14, 75.2 us).
__global__ __launch_bounds__(256, 2)
void conv_max_kernel(const float* __restrict__ x, const u16* __restrict__ wu,
                     const float* __restrict__ b3, const float* __restrict__ b4,
                     const float* __restrict__ b5, float* __restrict__ feats) {
  __shared__ __align__(16) char xs[A_BYTES];
  const int bid = blockIdx.x;
  const int b = bid >> 1, s0 = (bid & 1) * 64;
  const int tid = threadIdx.x;
  const int l = tid & 63, w = tid >> 6;
  const float* xb = x + (size_t)b * (SEQ * EMB);
  const char*  wB = (const char*)wu;

  // stage A: rows s0-2 .. s0+65 (68), 656 B stride, linear (r10-verified best)
  for (int t = tid; t < 68 * 80; t += 256) {
    int r = t / 80, cg = t - r * 80;
    int xr = s0 - 2 + r;
    float4 v = make_float4(0.f, 0.f, 0.f, 0.f);
    if (xr >= 0 && xr < SEQ && cg < 75)
      v = *reinterpret_cast<const float4*>(xb + xr * EMB + cg * 4);
    ushort4 h;
    h.x = f2bf(v.x); h.y = f2bf(v.y); h.z = f2bf(v.z); h.w = f2bf(v.w);
    *reinterpret_cast<ushort4*>(xs + r * AROW + cg * 8) = h;
  }
  __syncthreads();   // the only barrier: A visible to all 4 waves

  if (w == 0) {
    kloop_epi<4, 3>(xs, wB + 0,      l, s0,  0, b3, 126,   0, b, feats);
    kloop_epi<3, 3>(xs, wB + 122880, l, s0, 64, b3, 126,   0, b, feats);
  } else if (w == 1) {
    kloop_epi<4, 4>(xs, wB + 215040, l, s0,  0, b4, 127, 100, b, feats);
    kloop_epi<1, 5>(xs, wB + 378880, l, s0,  0, b5, 128, 200, b, feats);
  } else if (w == 2) {
    kloop_epi<3, 4>(xs, wB + 430080, l, s0, 64, b4, 127, 100, b, feats);
    kloop_epi<2, 5>(xs, wB + 552960, l, s0, 16, b5, 128, 200, b, feats);
  } else {
    kloop_epi<4, 5>(xs, wB + 655360, l, s0, 48, b5, 128, 200, b, feats);
  }
}

// feats[512,300] @ Wfc[5,300]^T + bfc -> log_softmax. One wave per row.
__global__ void fc_kernel(const float* __restrict__ feats, const float* __restrict__ Wfc,
                          const float* __restrict__ bfc, float* __restrict__ out) {
  const int b = blockIdx.x, l = threadIdx.x;
  float acc[5] = {0.f, 0.f, 0.f, 0.f, 0.f};
  for (int e = l; e < 300; e += 64) {
    float fv = feats[b * 300 + e];
    #pragma unroll
    for (int c = 0; c < 5; ++c) acc[c] += fv * Wfc[c * 300 + e];
  }
  #pragma unroll
  for (int off = 32; off; off >>= 1) {
    #pragma unroll
    for (int c = 0; c < 5; ++c) acc[c] += __shfl_down(acc[c], off);
  }
  if (l == 0) {
    float lg[5], m = -1e30f;
    #pragma unroll
    for (int c = 0; c < 5; ++c) { lg[c] = acc[c] + bfc[c]; m = fmaxf(m, lg[c]); }
    float se = 0.f;
    #pragma unroll
    for (int c = 0; c < 5; ++c) se += expf(lg[c] - m);
    float ls = logf(se);
    #pragma unroll
    for (int c = 0; c < 5; ++c) out[b * 5 + c] = lg[c] - m - ls;
  }
}

extern "C" void kernel_launch(void* const* d_in, const int* in_sizes, int n_in,
                              void* d_out, int out_size, void* d_ws, size_t ws_size,
                              hipStream_t stream) {
  const float* x   = (const float*)d_in[0];
  const float* w3  = (const float*)d_in[1];
  const float* b3  = (const float*)d_in[2];
  const float* w4  = (const float*)d_in[3];
  const float* b4  = (const float*)d_in[4];
  const float* w5  = (const float*)d_in[5];
  const float* b5  = (const float*)d_in[6];
  const float* Wfc = (const float*)d_in[7];
  const float* bfc = (const float*)d_in[8];
  float* out = (float*)d_out;

  u16*   wu    = (u16*)d_ws;
  float* feats = (float*)((char*)d_ws + OFF_FEATS);

  prep_weights<<<(PREP_TOT + 255) / 256, 256, 0, stream>>>(w3, w4, w5, wu, feats);
  conv_max_kernel<<<NB * 2, 256, 0, stream>>>(x, wu, b3, b4, b5, feats);
  fc_kernel<<<NB, 64, 0, stream>>>(feats, Wfc, bfc, out);
}